// Round 6
// baseline (3846.106 us; speedup 1.0000x reference)
//
#include <hip/hip_runtime.h>
#include <hip/hip_bf16.h>

// Problem constants (from reference)
#define BB    512
#define TT    128
#define HID   1024
#define EMBD  512
#define VOC   1024
#define OUTN  1024
#define DIMG  2048
#define FOURH 4096

typedef __attribute__((ext_vector_type(8))) short  short8;   // 8 bf16 (MFMA A/B frag)
typedef __attribute__((ext_vector_type(4))) float  f32x4;    // MFMA C/D frag
typedef unsigned int u32;

// Gate-interleaved column map: n' = G*64 + gate*16 + u -> original col = gate*1024 + G*16 + u
__device__ __forceinline__ int lstm_colmap(int n) {
    return ((n >> 4) & 3) * HID + ((n >> 6) << 4) + (n & 15);
}
__device__ __forceinline__ float sigmoidf_(float x) { return 1.0f / (1.0f + expf(-x)); }
__device__ __forceinline__ short f2bf(float x) { __hip_bfloat16 b = __float2bfloat16(x); return *(short*)&b; }
__device__ __forceinline__ float bf2f(short s) { __hip_bfloat16 b; *(short*)&b = s; return __bfloat162float(b); }

// async global->LDS, 16B per lane; lds base must be wave-uniform (HW adds lane*16)
__device__ __forceinline__ void async_cp16(void* lds, const void* g) {
    __builtin_amdgcn_global_load_lds((const __attribute__((address_space(1))) u32*)g,
                                     (__attribute__((address_space(3))) u32*)lds, 16, 0, 0);
}

// ---------------------------------------------------------------------------
// init: c=0, h0=0, out0 = bimg broadcast, out1 = bhid broadcast (split-K GEMMs atomicAdd on top)
__global__ void init2_k(float* __restrict__ c, short* __restrict__ h0,
                        float* __restrict__ o0, float* __restrict__ o1,
                        const float* __restrict__ bimg, const float* __restrict__ bhid) {
    int i = blockIdx.x * 256 + threadIdx.x;     // over 512*1024
    int n = i & (OUTN - 1);
    c[i] = 0.0f; h0[i] = 0;
    o0[i] = bimg[n]; o1[i] = bhid[n];
}

// ---------------------------------------------------------------------------
// f32 -> bf16 convert (4 elems/thread)
__global__ void cvt_k(const float* __restrict__ in, short* __restrict__ out, int n4) {
    int i = blockIdx.x * blockDim.x + threadIdx.x;
    if (i >= n4) return;
    float4 v = ((const float4*)in)[i];
    short4 o;
    o.x = f2bf(v.x); o.y = f2bf(v.y); o.z = f2bf(v.z); o.w = f2bf(v.w);
    ((short4*)out)[i] = o;
}

// ---------------------------------------------------------------------------
// Tiled transpose: out[n][k] = bf16(in[k][map(n)]).  32x32 tiles, 256 threads.
template<bool MAP>
__global__ void tr_k(const float* __restrict__ in, short* __restrict__ out, int K, int N_in) {
    __shared__ short tile[32][33];
    int n0 = blockIdx.x * 32, k0 = blockIdx.y * 32;
    int tx = threadIdx.x & 31, ty = threadIdx.x >> 5;   // 32 x 8
    int nsrc = MAP ? lstm_colmap(n0 + tx) : (n0 + tx);
#pragma unroll
    for (int j = 0; j < 4; j++) {
        int kw = ty + j * 8;
        tile[kw][tx] = f2bf(in[(size_t)(k0 + kw) * N_in + nsrc]);
    }
    __syncthreads();
#pragma unroll
    for (int j = 0; j < 4; j++) {
        int nw = ty + j * 8;
        out[(size_t)(n0 + nw) * K + k0 + tx] = tile[tx][nw];
    }
}

// ---------------------------------------------------------------------------
// Pipelined GEMM: acc = A[M,Kf](bf16) @ Bt[N,Kf](bf16) over k in [kbeg, kbeg+niter*64)
// A: async double-buffered LDS (global_load_lds w16, contiguous conflict-free planes).
// B: direct global->register fragments (each element used once per block — no LDS), 1-iter prefetch.
// One barrier per 64-K iter.  Tile 64x128, 4 waves 2x2 (wave 32x64).
// Epilogue: atomicAdd f32 (split-K partials onto bias-pre-initialized out) or bf16 store (+bias).
template<typename OutT, bool ATOMIC, bool MAPB>
__global__ __launch_bounds__(256) void gemm_bt_k(
    const short* __restrict__ A, const short* __restrict__ Bt,
    const float* __restrict__ bias, OutT* __restrict__ out,
    int Kf, int kbeg, int niter, int N)
{
    __shared__ __align__(16) short As[2][2][64 * 32];   // [buf][plane][row*32], 16 KB
    const int tid  = threadIdx.x;
    const int lane = tid & 63, wid = tid >> 6;
    const int wm = wid >> 1, wn = wid & 1;
    const int col16 = lane & 15, quad = lane >> 4;
    const int m0 = blockIdx.y * 64;
    const int n0 = blockIdx.x * 128;

    const int srow = wid * 16 + (lane >> 2);     // A staging: wave wid covers plane rows wid*16..+15
    const int scol = (lane & 3) * 8;
    const short* ag  = A  + (size_t)(m0 + srow) * Kf + kbeg + scol;
    const short* bp0 = Bt + (size_t)(n0 + wn * 64 + col16) * Kf + kbeg + quad * 8;

    f32x4 acc[2][4];
#pragma unroll
    for (int i = 0; i < 2; i++)
#pragma unroll
        for (int jj = 0; jj < 4; jj++) acc[i][jj] = (f32x4)0.0f;

    short8 bcur[4][2], bnxt[4][2];
    async_cp16(&As[0][0][wid * 512], ag);
    async_cp16(&As[0][1][wid * 512], ag + 32);
#pragma unroll
    for (int tc = 0; tc < 4; tc++)
#pragma unroll
        for (int p = 0; p < 2; p++) {
            bcur[tc][p] = *(const short8*)(bp0 + (size_t)tc * 16 * Kf + p * 32);
            bnxt[tc][p] = bcur[tc][p];
        }
    __syncthreads();   // A buf0 + bcur resident

    int buf = 0;
#pragma unroll 1
    for (int it = 0; it < niter; ++it) {
        if (it + 1 < niter) {
            const short* agn = ag + (it + 1) * 64;
            async_cp16(&As[buf ^ 1][0][wid * 512], agn);
            async_cp16(&As[buf ^ 1][1][wid * 512], agn + 32);
#pragma unroll
            for (int tc = 0; tc < 4; tc++)
#pragma unroll
                for (int p = 0; p < 2; p++)
                    bnxt[tc][p] = *(const short8*)(bp0 + (size_t)tc * 16 * Kf + (it + 1) * 64 + p * 32);
        }
        short8 afrag[2][2];
#pragma unroll
        for (int tr = 0; tr < 2; tr++)
#pragma unroll
            for (int p = 0; p < 2; p++)
                afrag[tr][p] = *(const short8*)&As[buf][p][(wm * 32 + tr * 16 + col16) * 32 + quad * 8];
#pragma unroll
        for (int p = 0; p < 2; p++)
#pragma unroll
            for (int tr = 0; tr < 2; tr++)
#pragma unroll
                for (int tc = 0; tc < 4; tc++)
                    acc[tr][tc] = __builtin_amdgcn_mfma_f32_16x16x32_bf16(afrag[tr][p], bcur[tc][p], acc[tr][tc], 0, 0, 0);
        __syncthreads();   // drains next-iter A/B loads; overlapped with MFMA above
#pragma unroll
        for (int tc = 0; tc < 4; tc++) { bcur[tc][0] = bnxt[tc][0]; bcur[tc][1] = bnxt[tc][1]; }
        buf ^= 1;
    }

#pragma unroll
    for (int tr = 0; tr < 2; tr++)
#pragma unroll
        for (int tc = 0; tc < 4; tc++) {
            int colg = n0 + wn * 64 + tc * 16 + col16;
            float bv = 0.0f;
            if constexpr (!ATOMIC) bv = bias[MAPB ? lstm_colmap(colg) : colg];
#pragma unroll
            for (int r = 0; r < 4; r++) {
                int rowg = m0 + wm * 32 + tr * 16 + quad * 4 + r;
                float v = acc[tr][tc][r] + bv;
                if constexpr (ATOMIC) atomicAdd((float*)&out[(size_t)rowg * N + colg], v);
                else                  out[(size_t)rowg * N + colg] = f2bf(v);
            }
        }
}

// ---------------------------------------------------------------------------
// LSTM step: gated = h_prev @ Wh_t + eproj[msg[:,t]] (bias folded), fused cell update.
// Same pipelined core; Kf=1024, 16 iters, grid (32, 8) = 256 blocks.
__global__ __launch_bounds__(256) void lstm_step_k(
    const short* __restrict__ h_prev, const short* __restrict__ Wh_t,
    const short* __restrict__ eproj, const int* __restrict__ msg, int t,
    float* __restrict__ c, short* __restrict__ h_next)
{
    constexpr int Kf = HID;
    __shared__ __align__(16) short As[2][2][64 * 32];
    const int tid  = threadIdx.x;
    const int lane = tid & 63, wid = tid >> 6;
    const int wm = wid >> 1, wn = wid & 1;
    const int col16 = lane & 15, quad = lane >> 4;
    const int m0 = blockIdx.y * 64;
    const int n0 = blockIdx.x * 128;

    const int srow = wid * 16 + (lane >> 2);
    const int scol = (lane & 3) * 8;
    const short* ag  = h_prev + (size_t)(m0 + srow) * Kf + scol;
    const short* bp0 = Wh_t   + (size_t)(n0 + wn * 64 + col16) * Kf + quad * 8;

    // prologue gathers: gate preacts (eproj) + c state; consumed after the K-loop
    const int G = (n0 + wn * 64) >> 6;
    const int j = G * 16 + col16;
    float ginit[2][4][4];
    float cold[2][4];
#pragma unroll
    for (int tr = 0; tr < 2; tr++)
#pragma unroll
        for (int r = 0; r < 4; r++) {
            int b = m0 + wm * 32 + tr * 16 + quad * 4 + r;
            int v = msg[b * TT + t];
            const short* ep = eproj + (size_t)v * FOURH + n0 + wn * 64 + col16;
#pragma unroll
            for (int tc = 0; tc < 4; tc++) ginit[tr][tc][r] = bf2f(ep[tc * 16]);
            cold[tr][r] = c[(size_t)b * HID + j];
        }

    f32x4 acc[2][4];
#pragma unroll
    for (int i = 0; i < 2; i++)
#pragma unroll
        for (int jj = 0; jj < 4; jj++) acc[i][jj] = (f32x4)0.0f;

    short8 bcur[4][2], bnxt[4][2];
    async_cp16(&As[0][0][wid * 512], ag);
    async_cp16(&As[0][1][wid * 512], ag + 32);
#pragma unroll
    for (int tc = 0; tc < 4; tc++)
#pragma unroll
        for (int p = 0; p < 2; p++) {
            bcur[tc][p] = *(const short8*)(bp0 + (size_t)tc * 16 * Kf + p * 32);
            bnxt[tc][p] = bcur[tc][p];
        }
    __syncthreads();

    int buf = 0;
#pragma unroll 1
    for (int it = 0; it < 16; ++it) {
        if (it + 1 < 16) {
            const short* agn = ag + (it + 1) * 64;
            async_cp16(&As[buf ^ 1][0][wid * 512], agn);
            async_cp16(&As[buf ^ 1][1][wid * 512], agn + 32);
#pragma unroll
            for (int tc = 0; tc < 4; tc++)
#pragma unroll
                for (int p = 0; p < 2; p++)
                    bnxt[tc][p] = *(const short8*)(bp0 + (size_t)tc * 16 * Kf + (it + 1) * 64 + p * 32);
        }
        short8 afrag[2][2];
#pragma unroll
        for (int tr = 0; tr < 2; tr++)
#pragma unroll
            for (int p = 0; p < 2; p++)
                afrag[tr][p] = *(const short8*)&As[buf][p][(wm * 32 + tr * 16 + col16) * 32 + quad * 8];
#pragma unroll
        for (int p = 0; p < 2; p++)
#pragma unroll
            for (int tr = 0; tr < 2; tr++)
#pragma unroll
                for (int tc = 0; tc < 4; tc++)
                    acc[tr][tc] = __builtin_amdgcn_mfma_f32_16x16x32_bf16(afrag[tr][p], bcur[tc][p], acc[tr][tc], 0, 0, 0);
        __syncthreads();
#pragma unroll
        for (int tc = 0; tc < 4; tc++) { bcur[tc][0] = bnxt[tc][0]; bcur[tc][1] = bnxt[tc][1]; }
        buf ^= 1;
    }

    // Fused LSTM cell update. tc == gate {i,g,f,o}; hidden unit j shared across tc per lane.
#pragma unroll
    for (int tr = 0; tr < 2; tr++) {
#pragma unroll
        for (int r = 0; r < 4; r++) {
            int b = m0 + wm * 32 + tr * 16 + quad * 4 + r;
            float i_ = acc[tr][0][r] + ginit[tr][0][r];
            float g_ = acc[tr][1][r] + ginit[tr][1][r];
            float f_ = acc[tr][2][r] + ginit[tr][2][r];
            float o_ = acc[tr][3][r] + ginit[tr][3][r];
            size_t idx = (size_t)b * HID + j;
            float cn = sigmoidf_(f_ + 1.0f) * cold[tr][r] + sigmoidf_(i_) * tanhf(g_);
            c[idx] = cn;
            h_next[idx] = f2bf(sigmoidf_(o_) * tanhf(cn));
        }
    }
}

// ---------------------------------------------------------------------------
extern "C" void kernel_launch(void* const* d_in, const int* in_sizes, int n_in,
                              void* d_out, int out_size, void* d_ws, size_t ws_size,
                              hipStream_t stream) {
    const float* images = (const float*)d_in[0];
    const float* embed  = (const float*)d_in[1];
    const float* Wcell  = (const float*)d_in[2];
    const float* bcell  = (const float*)d_in[3];
    const float* Wimg   = (const float*)d_in[4];
    const float* bimg   = (const float*)d_in[5];
    const float* Whid   = (const float*)d_in[6];
    const float* bhid   = (const float*)d_in[7];
    const int*   msg    = (const int*)d_in[8];

    float* out0 = (float*)d_out;                   // images_encoded [512,1024] f32
    float* out1 = out0 + (size_t)BB * OUTN;        // hidden_encoded [512,1024] f32

    // Workspace layout (33 MB)
    char* ws = (char*)d_ws;
    const size_t MB = 1024 * 1024;
    short* Wh_t    = (short*)(ws);            //  8 MB [4096][1024] bf16, colmapped
    short* Wx_t    = (short*)(ws + 8 * MB);   //  4 MB [4096][512]  bf16, colmapped
    short* Wimg_t  = (short*)(ws + 12 * MB);  //  4 MB [1024][2048] bf16
    short* Whid_t  = (short*)(ws + 16 * MB);  //  2 MB [1024][1024] bf16
    short* eproj   = (short*)(ws + 18 * MB);  //  8 MB [1024][4096] bf16, bias folded
    short* h_a     = (short*)(ws + 26 * MB);  //  1 MB
    short* h_b     = (short*)(ws + 27 * MB);  //  1 MB
    float* cbuf    = (float*)(ws + 28 * MB);  //  2 MB
    short* imgs_c  = (short*)(ws + 30 * MB);  //  2 MB [512][2048] bf16
    short* embed_c = (short*)(ws + 32 * MB);  //  1 MB [1024][512] bf16

    // init state + bias broadcast into outputs (split-K GEMMs atomicAdd partials on top)
    init2_k<<<dim3((BB * HID) / 256), dim3(256), 0, stream>>>(cbuf, h_a, out0, out1, bimg, bhid);

    // f32 -> bf16 A-operands
    cvt_k<<<dim3((BB * DIMG / 4) / 256), dim3(256), 0, stream>>>(images, imgs_c, BB * DIMG / 4);
    cvt_k<<<dim3((VOC * EMBD / 4) / 256), dim3(256), 0, stream>>>(embed, embed_c, VOC * EMBD / 4);

    // weight transposes (tiled, f32 -> bf16, colmap for the LSTM pair)
    tr_k<true ><<<dim3(FOURH / 32, HID / 32),  dim3(256), 0, stream>>>(Wcell + (size_t)EMBD * FOURH, Wh_t, HID, FOURH);
    tr_k<true ><<<dim3(FOURH / 32, EMBD / 32), dim3(256), 0, stream>>>(Wcell, Wx_t, EMBD, FOURH);
    tr_k<false><<<dim3(OUTN / 32, DIMG / 32),  dim3(256), 0, stream>>>(Wimg, Wimg_t, DIMG, OUTN);
    tr_k<false><<<dim3(OUTN / 32, HID / 32),   dim3(256), 0, stream>>>(Whid, Whid_t, HID, OUTN);

    // eproj = bf16(embed @ W_x + b_cell), gate-interleaved  (M=1024, N=4096, K=512, 512 blocks)
    gemm_bt_k<short, false, true><<<dim3(FOURH / 128, VOC / 64), dim3(256), 0, stream>>>(
        embed_c, Wx_t, bcell, eproj, EMBD, 0, EMBD / 64, FOURH);

    // images_encoded: split-K=4 atomic partials  (M=512, N=1024, K=2048 -> 4 x 512)
    for (int z = 0; z < 4; z++)
        gemm_bt_k<float, true, false><<<dim3(OUTN / 128, BB / 64), dim3(256), 0, stream>>>(
            imgs_c, Wimg_t, nullptr, out0, DIMG, z * 512, 8, OUTN);

    // 128 sequential LSTM steps, ping-pong h (t=127 writes h_a)
    for (int t = 0; t < TT; t++) {
        const short* hp = (t & 1) ? h_b : h_a;
        short* hn       = (t & 1) ? h_a : h_b;
        lstm_step_k<<<dim3(FOURH / 128, BB / 64), dim3(256), 0, stream>>>(
            hp, Wh_t, eproj, msg, t, cbuf, hn);
    }

    // hidden_encoded: split-K=4 atomic partials  (M=512, N=1024, K=1024 -> 4 x 256)
    for (int z = 0; z < 4; z++)
        gemm_bt_k<float, true, false><<<dim3(OUTN / 128, BB / 64), dim3(256), 0, stream>>>(
            h_a, Whid_t, nullptr, out1, HID, z * 256, 4, OUTN);
}